// Round 13
// baseline (108.452 us; speedup 1.0000x reference)
//
#include <hip/hip_runtime.h>

// Problem dims (fixed by setup_inputs): x [B,N,C], adapter dim D, patch grid HxH
#define B_  64
#define N_  1024
#define H_  32
#define C_  768
#define D_  8

#define QCHUNKS   4
#define IMG_PER_Q (B_ / QCHUNKS)          // 16 images per chunk
#define ROWS_PER_Q (IMG_PER_Q * N_)       // 16384 rows
#define NDOWN     512                     // down-role blocks per chunk (32 rows each)
#define NUP       (IMG_PER_Q * 4)         // convup-role blocks per chunk (64)

__device__ __forceinline__ float qgelu(float v) {
    return v / (1.0f + __expf(-1.702f * v));
}

typedef float f32x4_t __attribute__((ext_vector_type(4)));
__device__ __forceinline__ float4 ntload4(const float4* p) {
    f32x4_t v = __builtin_nontemporal_load((const f32x4_t*)p);
    return make_float4(v.x, v.y, v.z, v.w);
}
__device__ __forceinline__ void ntstore4(float4 v, float4* p) {
    f32x4_t t; t.x = v.x; t.y = v.y; t.z = v.z; t.w = v.w;
    __builtin_nontemporal_store(t, (f32x4_t*)p);
}

// 10-shuffle butterfly reduce over d=8 (see earlier rounds).
__device__ __forceinline__ void reduce8(float* acc, int lane) {
    {
        const bool hi = lane & 1;
#pragma unroll
        for (int j = 0; j < 4; ++j) {
            const float a = acc[j], b = acc[j + 4];
            acc[j] = hi ? b : a;
            acc[j + 4] = hi ? a : b;
        }
#pragma unroll
        for (int j = 0; j < 4; ++j)
            acc[j] += __shfl_xor(acc[j + 4], 1, 64);
    }
    {
        const bool hi = lane & 2;
#pragma unroll
        for (int j = 0; j < 2; ++j) {
            const float a = acc[j], b = acc[j + 2];
            acc[j] = hi ? b : a;
            acc[j + 2] = hi ? a : b;
        }
#pragma unroll
        for (int j = 0; j < 2; ++j)
            acc[j] += __shfl_xor(acc[j + 2], 2, 64);
    }
    {
        const bool hi = lane & 4;
        const float a = acc[0], b = acc[1];
        acc[0] = hi ? b : a;
        acc[1] = hi ? a : b;
        acc[0] += __shfl_xor(acc[1], 4, 64);
    }
    acc[0] += __shfl_xor(acc[0], 8, 64);
    acc[0] += __shfl_xor(acc[0], 16, 64);
    acc[0] += __shfl_xor(acc[0], 32, 64);
}

// ---------------- k_step: software-pipelined chunk step ---------------------
// Blocks [0, nDown): DOWN role = v12's k_down for chunk rows
//   [downBase, downBase + 32*nDown). 24 KB LDS weight transpose, nt x loads,
//   wave per row-pair (4 pairs/wave).
// Blocks [nDown, nDown+64): CONVUP role for chunk upImg0..+15 = conv3x3 +
//   qgelu from t1 (L2-hot) + up-projection with register Wu + nt out stores.
// Roles are independent (different data) -> reads of chunk s overlap writes
// of chunk s-1 on the fabric within one launch.
__global__ __launch_bounds__(256) void k_step(
    const float* __restrict__ x,  const float* __restrict__ Wd,
    const float* __restrict__ bd, float* __restrict__ t1,
    const float* __restrict__ Wc, const float* __restrict__ bc,
    const float* __restrict__ Wu, const float* __restrict__ bu,
    float* __restrict__ out, int downBase, int nDown, int upImg0)
{
    __shared__ float smem[D_ * C_];          // 24 KB, role-dependent layout

    const int wid  = threadIdx.x >> 6;
    const int lane = threadIdx.x & 63;

    if ((int)blockIdx.x < nDown) {
        // ------------------------- DOWN role -----------------------------
        float* sW = smem;                    // sW[d*C_ + c] = Wd[c*D_ + d]
        for (int i = threadIdx.x; i < D_ * C_; i += 256) {
            const int c = i >> 3, d = i & 7;
            sW[d * C_ + c] = Wd[i];
        }
        __syncthreads();

        const int dl = 4 * (lane & 1) + 2 * ((lane >> 1) & 1) + ((lane >> 2) & 1);
        const float bias = bd[dl];
        const int pairBase = (downBase >> 1) + blockIdx.x * 16 + wid * 4;

#pragma unroll 1
        for (int i = 0; i < 4; ++i) {
            const int p = pairBase + i;
            const float4* x0 = (const float4*)(x + (size_t)(2 * p) * C_);
            const float4* x1 = x0 + (C_ / 4);

            float4 va[3], vb[3];
#pragma unroll
            for (int k = 0; k < 3; ++k) {
                va[k] = ntload4(&x0[k * 64 + lane]);
                vb[k] = ntload4(&x1[k * 64 + lane]);
            }

            float a0[D_], a1[D_];
#pragma unroll
            for (int d = 0; d < D_; ++d) { a0[d] = 0.0f; a1[d] = 0.0f; }

#pragma unroll
            for (int k = 0; k < 3; ++k) {
#pragma unroll
                for (int d = 0; d < D_; ++d) {
                    const float4 wv = *(const float4*)&sW[d * C_ + (k * 64 + lane) * 4];
                    a0[d] += va[k].x * wv.x + va[k].y * wv.y
                           + va[k].z * wv.z + va[k].w * wv.w;
                    a1[d] += vb[k].x * wv.x + vb[k].y * wv.y
                           + vb[k].z * wv.z + vb[k].w * wv.w;
                }
            }

            reduce8(a0, lane);
            reduce8(a1, lane);

            if (lane < 16) {
                const float s = (lane & 8) ? a1[0] : a0[0];
                t1[(size_t)(2 * p + ((lane >> 3) & 1)) * D_ + dl] = qgelu(s + bias);
            }
        }
    } else {
        // ------------------------ CONVUP role ----------------------------
        float* sIn = smem;                   // [10][32][8] = 2560
        float* sT2 = smem + 2560;            // [8][32][8]  = 2048
        float* sWc = smem + 4608;            // 576
        float* sbc = smem + 5184;            // 8

        const int idx   = blockIdx.x - nDown;
        const int img   = upImg0 + (idx >> 2);
        const int strip = idx & 3;
        const int h0    = strip * 8;
        const float* in = t1 + (size_t)img * N_ * D_;

        // stage conv input (10 rows, zero-padded) + conv weights
#pragma unroll
        for (int j = 0; j < 10; ++j) {
            const int i   = threadIdx.x + j * 256;
            const int lr  = i >> 8;
            const int rem = i & 255;
            const int g   = h0 - 1 + lr;
            sIn[i] = (g >= 0 && g < H_) ? in[(size_t)g * H_ * D_ + rem] : 0.0f;
        }
        for (int i = threadIdx.x; i < 9 * D_ * D_; i += 256) sWc[i] = Wc[i];
        if (threadIdx.x < D_) sbc[threadIdx.x] = bc[threadIdx.x];

        // up-projection weights into registers (L2-hot, reused 64x/lane)
        float4 wu[3][D_];
        float4 ub[3];
#pragma unroll
        for (int j = 0; j < 3; ++j) {
            ub[j] = *(const float4*)&bu[(lane + j * 64) * 4];
#pragma unroll
            for (int d = 0; d < D_; ++d)
                wu[j][d] = *(const float4*)&Wu[d * C_ + (lane + j * 64) * 4];
        }
        __syncthreads();

        // conv3x3 + bias + qgelu: one pixel per thread
        {
            const int lh = threadIdx.x >> 5;
            const int w  = threadIdx.x & 31;
            float acc[D_];
#pragma unroll
            for (int co = 0; co < D_; ++co) acc[co] = sbc[co];
#pragma unroll
            for (int kh = 0; kh < 3; ++kh) {
                const int lrow = lh + kh;
#pragma unroll
                for (int kw = 0; kw < 3; ++kw) {
                    const int ww = w + kw - 1;
                    if (ww < 0 || ww >= H_) continue;
                    const float* ip = &sIn[(lrow * H_ + ww) * D_];
                    const float* wp = &sWc[(kh * 3 + kw) * D_ * D_];
#pragma unroll
                    for (int ci = 0; ci < D_; ++ci) {
                        const float iv = ip[ci];
#pragma unroll
                        for (int co = 0; co < D_; ++co)
                            acc[co] += iv * wp[ci * D_ + co];
                    }
                }
            }
            float* tp = &sT2[(lh * H_ + w) * D_];
#pragma unroll
            for (int co = 0; co < D_; ++co) tp[co] = qgelu(acc[co]);
        }
        __syncthreads();

        // up: wave handles 64 of the strip's 256 positions; nt stores
        const size_t rowBase = (size_t)img * N_ + strip * 256;
#pragma unroll 1
        for (int r = 0; r < 64; ++r) {
            const int  row = wid * 64 + r;
            const float* tv = &sT2[row * D_];
            float rv[D_];
#pragma unroll
            for (int d = 0; d < D_; ++d) rv[d] = tv[d];

            float* orow = out + (rowBase + row) * C_;
#pragma unroll
            for (int j = 0; j < 3; ++j) {
                float4 o = ub[j];
#pragma unroll
                for (int d = 0; d < D_; ++d) {
                    o.x += rv[d] * wu[j][d].x;
                    o.y += rv[d] * wu[j][d].y;
                    o.z += rv[d] * wu[j][d].z;
                    o.w += rv[d] * wu[j][d].w;
                }
                ntstore4(o, (float4*)&orow[(lane + j * 64) * 4]);
            }
        }
    }
}

extern "C" void kernel_launch(void* const* d_in, const int* in_sizes, int n_in,
                              void* d_out, int out_size, void* d_ws, size_t ws_size,
                              hipStream_t stream) {
    const float* x  = (const float*)d_in[0];
    const float* Wd = (const float*)d_in[1];
    const float* bd = (const float*)d_in[2];
    const float* Wc = (const float*)d_in[3];
    const float* bc = (const float*)d_in[4];
    const float* Wu = (const float*)d_in[5];
    const float* bu = (const float*)d_in[6];
    float* out = (float*)d_out;

    float* t1 = (float*)d_ws;   // [65536][8] down+gelu output (4 MB ws ok)

    // Pipelined schedule: step s runs down(chunk s) overlapped with
    // convup(chunk s-1) in ONE launch (disjoint block roles).
    for (int s = 0; s <= QCHUNKS; ++s) {
        const int nDown  = (s < QCHUNKS) ? NDOWN : 0;
        const int nUp    = (s > 0) ? NUP : 0;
        const int grid   = nDown + nUp;
        const int dBase  = s * ROWS_PER_Q;
        const int uImg0  = (s - 1) * IMG_PER_Q;
        k_step<<<grid, 256, 0, stream>>>(x, Wd, bd, t1, Wc, bc, Wu, bu, out,
                                         dBase, nDown, uImg0);
    }
}